// Round 2
// baseline (668.797 us; speedup 1.0000x reference)
//
#include <hip/hip_runtime.h>
#include <hip/hip_cooperative_groups.h>

namespace cg = cooperative_groups;

// LinearAttention: out[b,n,v] = sum_k q[b,k,n] * ktv[b,k,v],
//                  ktv[b,k,v] = sum_n K[b,n,k] * V[b,n,v]
// B=16, DK=64, N=8192, DV=64, fp32.
//
// R10: fused cooperative kernel, spill-free.
//  - R9 post-mortem: __launch_bounds__(256,4) forced VGPR=64 but kernel
//    needs ~130 -> scratch spill (WRITE 163MB vs 49MB algorithmic),
//    fused 295us at 567GB/s. Fusion itself launched fine.
//  - Fix: 512 blocks (2/CU), __launch_bounds__(256,2) -> VGPR cap 256.
//    Each block: 256 rows in A (4 batches/wave), 256 n in C (2 iters,
//    ktv LDS amortized 2x). part halves to 8.4MB (32 chunks).
//  - Phase B: 512 blocks x 128 outputs, wave w sums 8 chunks with
//    fully-coalesced 256B loads, LDS cross-wave combine. Deterministic.
// Floors: A 72.8MB -> 11.6us; B 8.7MB -> 1.4us; C 64MB -> 10.2us.

#define B_   16
#define N_   8192
#define DK_  64
#define DV_  64
#define CH_  32      // chunks; 256 rows/block, 64 rows/wave

// ==================== fused cooperative kernel ====================
__global__ __launch_bounds__(256, 2) void fused(
    const float* __restrict__ q, const float* __restrict__ K,
    const float* __restrict__ V, float* __restrict__ part,
    float* __restrict__ ktv, float* __restrict__ out)
{
    __shared__ float sm[4][2048];   // 32 KB, reused across phases

    const int c = blockIdx.x, b = blockIdx.y, t = threadIdx.x;
    const int w = t >> 6, lane = t & 63;

    // ---------------- Phase A: partial K^T V ----------------
    {
        const int kk = (lane >> 3) * 8;   // 8 k-groups of 8
        const int vv = (lane & 7) * 8;    // 8 v-groups of 8
        float* Ksw = &sm[w][0];
        float* Vsw = &sm[w][1024];

        // wave handles 64 rows: 4 batches of 16
        const size_t row0 = (size_t)b * N_ + (size_t)c * 256 + (size_t)w * 64;
        const float4* K4 = (const float4*)(K + row0 * DK_);   // 1024 f4
        const float4* V4 = (const float4*)(V + row0 * DV_);

        float acc[8][8] = {};

        #pragma unroll
        for (int r = 0; r < 4; ++r) {
            float4 kb_[4], vb_[4];
            #pragma unroll
            for (int j = 0; j < 4; ++j) kb_[j] = K4[r * 256 + j * 64 + lane];
            #pragma unroll
            for (int j = 0; j < 4; ++j) vb_[j] = V4[r * 256 + j * 64 + lane];
            #pragma unroll
            for (int j = 0; j < 4; ++j) {
                ((float4*)Ksw)[j * 64 + lane] = kb_[j];
                ((float4*)Vsw)[j * 64 + lane] = vb_[j];
            }
            // wave-private staging: no barrier needed (DS ordering per-wave)
            #pragma unroll 4
            for (int n = 0; n < 16; ++n) {
                alignas(16) float fk[8], fv[8];
                *(float4*)&fk[0] = *(const float4*)&Ksw[n * 64 + kk];
                *(float4*)&fk[4] = *(const float4*)&Ksw[n * 64 + kk + 4];
                *(float4*)&fv[0] = *(const float4*)&Vsw[n * 64 + vv];
                *(float4*)&fv[4] = *(const float4*)&Vsw[n * 64 + vv + 4];
                #pragma unroll
                for (int i = 0; i < 8; ++i)
                    #pragma unroll
                    for (int j = 0; j < 8; ++j)
                        acc[i][j] += fk[i] * fv[j];
            }
        }

        // staged cross-wave reduce in red[4096] (= sm reused).
        __syncthreads();
        float* red = &sm[0][0];
        if (w == 0) {
            #pragma unroll
            for (int i = 0; i < 8; ++i) {
                *(float4*)&red[(kk + i) * 64 + vv]     = make_float4(acc[i][0], acc[i][1], acc[i][2], acc[i][3]);
                *(float4*)&red[(kk + i) * 64 + vv + 4] = make_float4(acc[i][4], acc[i][5], acc[i][6], acc[i][7]);
            }
        }
        __syncthreads();
        #pragma unroll
        for (int ww = 1; ww < 4; ++ww) {
            if (w == ww) {
                #pragma unroll
                for (int i = 0; i < 8; ++i) {
                    float4 r0 = *(float4*)&red[(kk + i) * 64 + vv];
                    float4 r1 = *(float4*)&red[(kk + i) * 64 + vv + 4];
                    r0.x += acc[i][0]; r0.y += acc[i][1]; r0.z += acc[i][2]; r0.w += acc[i][3];
                    r1.x += acc[i][4]; r1.y += acc[i][5]; r1.z += acc[i][6]; r1.w += acc[i][7];
                    *(float4*)&red[(kk + i) * 64 + vv]     = r0;
                    *(float4*)&red[(kk + i) * 64 + vv + 4] = r1;
                }
            }
            __syncthreads();
        }

        float4* P = (float4*)(part + ((size_t)c * B_ + b) * 4096);
        #pragma unroll
        for (int j = 0; j < 4; ++j)
            P[t + 256 * j] = ((const float4*)red)[t + 256 * j];
    }

    __threadfence();
    cg::this_grid().sync();

    // ---------------- Phase B: reduce 32 partials -> ktv ----------------
    // 512 blocks x 128 outputs. Wave w sums chunks [w*8, w*8+8), each
    // load = 64 consecutive floats (256B, coalesced). LDS combine.
    {
        const int fb = b * CH_ + c;                // 0..511
        const int o0 = fb * 128;                   // = b*4096 + c*128
        float s0 = 0.f, s1 = 0.f;
        #pragma unroll
        for (int u = 0; u < 8; ++u) {
            const size_t base = (size_t)(w * 8 + u) * 65536 + o0;
            s0 += part[base + lane];
            s1 += part[base + 64 + lane];
        }
        float* red = &sm[0][0];                    // 4*128 partials
        red[w * 128 + lane]      = s0;
        red[w * 128 + 64 + lane] = s1;
        __syncthreads();
        if (t < 128) {
            ktv[o0 + t] = red[t] + red[128 + t] + red[256 + t] + red[384 + t];
        }
    }

    __threadfence();
    cg::this_grid().sync();

    // ---------------- Phase C: out = q^T ktv ----------------
    // Block covers 256 n (2 iters of wave-32n body); ktv LDS reused 256x.
    {
        float* ks = &sm[0][0];   // 16 KB: ktv[b], [k][v]
        const int nl = (lane >> 3) * 4;  // 8 n-groups of 4
        const int vl = (lane & 7) * 8;   // 8 v-groups of 8

        const float4* kt4 = (const float4*)(ktv + (size_t)b * 4096);
        #pragma unroll
        for (int j = 0; j < 4; ++j)
            ((float4*)ks)[t + 256 * j] = kt4[t + 256 * j];
        __syncthreads();

        #pragma unroll
        for (int it = 0; it < 2; ++it) {
            const int n0 = c * 256 + w * 64 + it * 32;
            const float* ql = q + (size_t)b * DK_ * N_ + n0 + nl;

            float acc2[4][8] = {};
            #pragma unroll
            for (int kb = 0; kb < 4; ++kb) {
                alignas(16) float fq[16][4];
                #pragma unroll
                for (int u = 0; u < 16; ++u)
                    *(float4*)&fq[u][0] = *(const float4*)(ql + (size_t)(kb * 16 + u) * N_);
                #pragma unroll
                for (int u = 0; u < 16; ++u) {
                    const int k = kb * 16 + u;
                    alignas(16) float fv[8];
                    *(float4*)&fv[0] = *(const float4*)&ks[k * 64 + vl];
                    *(float4*)&fv[4] = *(const float4*)&ks[k * 64 + vl + 4];
                    #pragma unroll
                    for (int i = 0; i < 4; ++i)
                        #pragma unroll
                        for (int j = 0; j < 8; ++j)
                            acc2[i][j] += fq[u][i] * fv[j];
                }
            }

            float* ob = out + ((size_t)b * N_ + n0 + nl) * DV_ + vl;
            #pragma unroll
            for (int i = 0; i < 4; ++i) {
                *(float4*)&ob[(size_t)i * DV_]     = make_float4(acc2[i][0], acc2[i][1], acc2[i][2], acc2[i][3]);
                *(float4*)&ob[(size_t)i * DV_ + 4] = make_float4(acc2[i][4], acc2[i][5], acc2[i][6], acc2[i][7]);
            }
        }
    }
}

// ==================== fallback: proven 3-kernel path (R8) ====================
__global__ __launch_bounds__(256) void p1_partial(
    const float* __restrict__ K, const float* __restrict__ V,
    float* __restrict__ part)
{
    __shared__ float sm[4][2048];

    const int c = blockIdx.x, b = blockIdx.y, t = threadIdx.x;
    const int w = t >> 6, lane = t & 63;
    const int kk = (lane >> 3) * 8;
    const int vv = (lane & 7) * 8;
    float* Ksw = &sm[w][0];
    float* Vsw = &sm[w][1024];

    const size_t row0 = (size_t)b * N_ + (size_t)c * 256 + (size_t)w * 64;
    const float4* K4 = (const float4*)(K + row0 * DK_);
    const float4* V4 = (const float4*)(V + row0 * DV_);

    float acc[8][8] = {};

    #pragma unroll
    for (int r = 0; r < 4; ++r) {
        float4 kb_[4], vb_[4];
        #pragma unroll
        for (int j = 0; j < 4; ++j) kb_[j] = K4[r * 256 + j * 64 + lane];
        #pragma unroll
        for (int j = 0; j < 4; ++j) vb_[j] = V4[r * 256 + j * 64 + lane];
        #pragma unroll
        for (int j = 0; j < 4; ++j) {
            ((float4*)Ksw)[j * 64 + lane] = kb_[j];
            ((float4*)Vsw)[j * 64 + lane] = vb_[j];
        }
        #pragma unroll 4
        for (int n = 0; n < 16; ++n) {
            alignas(16) float fk[8], fv[8];
            *(float4*)&fk[0] = *(const float4*)&Ksw[n * 64 + kk];
            *(float4*)&fk[4] = *(const float4*)&Ksw[n * 64 + kk + 4];
            *(float4*)&fv[0] = *(const float4*)&Vsw[n * 64 + vv];
            *(float4*)&fv[4] = *(const float4*)&Vsw[n * 64 + vv + 4];
            #pragma unroll
            for (int i = 0; i < 8; ++i)
                #pragma unroll
                for (int j = 0; j < 8; ++j)
                    acc[i][j] += fk[i] * fv[j];
        }
    }

    __syncthreads();
    float* red = &sm[0][0];
    if (w == 0) {
        #pragma unroll
        for (int i = 0; i < 8; ++i) {
            *(float4*)&red[(kk + i) * 64 + vv]     = make_float4(acc[i][0], acc[i][1], acc[i][2], acc[i][3]);
            *(float4*)&red[(kk + i) * 64 + vv + 4] = make_float4(acc[i][4], acc[i][5], acc[i][6], acc[i][7]);
        }
    }
    __syncthreads();
    #pragma unroll
    for (int ww = 1; ww < 4; ++ww) {
        if (w == ww) {
            #pragma unroll
            for (int i = 0; i < 8; ++i) {
                float4 r0 = *(float4*)&red[(kk + i) * 64 + vv];
                float4 r1 = *(float4*)&red[(kk + i) * 64 + vv + 4];
                r0.x += acc[i][0]; r0.y += acc[i][1]; r0.z += acc[i][2]; r0.w += acc[i][3];
                r1.x += acc[i][4]; r1.y += acc[i][5]; r1.z += acc[i][6]; r1.w += acc[i][7];
                *(float4*)&red[(kk + i) * 64 + vv]     = r0;
                *(float4*)&red[(kk + i) * 64 + vv + 4] = r1;
            }
        }
        __syncthreads();
    }

    float4* P = (float4*)(part + ((size_t)c * B_ + b) * 4096);
    #pragma unroll
    for (int j = 0; j < 4; ++j)
        P[t + 256 * j] = ((const float4*)red)[t + 256 * j];
}

__global__ __launch_bounds__(256) void p1_reduce(
    const float* __restrict__ part, float* __restrict__ ktv)
{
    const int idx = blockIdx.x * 256 + threadIdx.x;
    float s = 0.f;
    #pragma unroll 16
    for (int c = 0; c < CH_; ++c)
        s += part[(size_t)c * 65536 + idx];
    ktv[idx] = s;
}

__global__ __launch_bounds__(256) void p2(
    const float* __restrict__ q, const float* __restrict__ ktv,
    float* __restrict__ out)
{
    __shared__ float ks[4096];

    const int nb = blockIdx.x, b = blockIdx.y, t = threadIdx.x;
    const int w = t >> 6, lane = t & 63;
    const int nl = (lane >> 3) * 4;
    const int vl = (lane & 7) * 8;
    const int n0 = nb * 128 + w * 32;

    const float4* kt4 = (const float4*)(ktv + (size_t)b * 4096);
    #pragma unroll
    for (int j = 0; j < 4; ++j)
        ((float4*)ks)[t + 256 * j] = kt4[t + 256 * j];
    __syncthreads();

    const float* ql = q + (size_t)b * DK_ * N_ + n0 + nl;

    float acc[4][8] = {};
    #pragma unroll
    for (int kb = 0; kb < 4; ++kb) {
        alignas(16) float fq[16][4];
        #pragma unroll
        for (int u = 0; u < 16; ++u)
            *(float4*)&fq[u][0] = *(const float4*)(ql + (size_t)(kb * 16 + u) * N_);
        #pragma unroll
        for (int u = 0; u < 16; ++u) {
            const int k = kb * 16 + u;
            alignas(16) float fv[8];
            *(float4*)&fv[0] = *(const float4*)&ks[k * 64 + vl];
            *(float4*)&fv[4] = *(const float4*)&ks[k * 64 + vl + 4];
            #pragma unroll
            for (int i = 0; i < 4; ++i)
                #pragma unroll
                for (int j = 0; j < 8; ++j)
                    acc[i][j] += fq[u][i] * fv[j];
        }
    }

    float* ob = out + ((size_t)b * N_ + n0 + nl) * DV_ + vl;
    #pragma unroll
    for (int i = 0; i < 4; ++i) {
        *(float4*)&ob[(size_t)i * DV_]     = make_float4(acc[i][0], acc[i][1], acc[i][2], acc[i][3]);
        *(float4*)&ob[(size_t)i * DV_ + 4] = make_float4(acc[i][4], acc[i][5], acc[i][6], acc[i][7]);
    }
}

extern "C" void kernel_launch(void* const* d_in, const int* in_sizes, int n_in,
                              void* d_out, int out_size, void* d_ws, size_t ws_size,
                              hipStream_t stream)
{
    (void)in_sizes; (void)n_in; (void)out_size; (void)ws_size;
    const float* q = (const float*)d_in[0];   // [16, 64, 8192]
    const float* k = (const float*)d_in[1];   // [16, 8192, 64]
    const float* v = (const float*)d_in[2];   // [16, 8192, 64]
    float* out = (float*)d_out;               // [16, 8192, 64]

    // ws: [32][16][4096] partials (8.4 MB) + [16][4096] ktv (256 KB)
    float* part = (float*)d_ws;
    float* ktv  = part + (size_t)CH_ * B_ * 4096;

    void* args[] = { (void*)&q, (void*)&k, (void*)&v,
                     (void*)&part, (void*)&ktv, (void*)&out };
    hipError_t e = hipLaunchCooperativeKernel(
        reinterpret_cast<void*>(fused), dim3(CH_, B_), dim3(256),
        args, 0, stream);
    if (e != hipSuccess) {
        (void)hipGetLastError();   // clear; fall back to 3-kernel path
        p1_partial<<<dim3(CH_, B_), 256, 0, stream>>>(k, v, part);
        p1_reduce<<<dim3(256), 256, 0, stream>>>(part, ktv);
        p2<<<dim3(64, B_), 256, 0, stream>>>(q, ktv, out);
    }
}

// Round 4
// 152.913 us; speedup vs baseline: 4.3737x; 4.3737x over previous
//
#include <hip/hip_runtime.h>

// LinearAttention: out[b,n,v] = sum_k q[b,k,n] * ktv[b,k,v],
//                  ktv[b,k,v] = sum_n K[b,n,k] * V[b,n,v]
// B=16, DK=64, N=8192, DV=64, fp32.
//
// R12: restore R8 verbatim (best clean pass: 149.9 us).
//  - R9-R11 post-mortem: fused cooperative variants either spilled
//    (launch_bounds min-waves halves the VGPR target: R9 WRITE 163MB,
//    R10 WRITE 664MB vs 41MB algorithmic) or crashed (R11). Residual
//    (total - kernel time) is ~110-130us for BOTH 1-kernel and 3-kernel
//    runs -> inter-kernel gaps ~0; residual = 256MiB ws poison fill
//    (~40us @83% peak) + harness reset memsets + graph overhead, all
//    harness-fixed. Fusion upside ~= its own grid-sync cost. Abandoned.
//  - Kernels total ~33us vs ~25us HBM floor; top-5 dispatches are all
//    harness fills. This is the controllable floor.
// Floors: p1 80 MB -> 12.7 us; reduce 16.7 MB -> 2.7 us; p2 64 MB -> 10.2 us.

#define B_   16
#define N_   8192
#define DK_  64
#define DV_  64
#define CH_  64      // p1 chunks; 128 rows/block, 32 rows/wave, 2 rounds of 16

// ---------------- Phase 1: partial K^T V ----------------
// grid (64, 16), 256 threads (4 waves). Wave w rows [w*32, w*32+32).
__global__ __launch_bounds__(256) void p1_partial(
    const float* __restrict__ K, const float* __restrict__ V,
    float* __restrict__ part)
{
    __shared__ float sm[4][2048];   // 32 KB; wave w: K rows [0..1023], V rows [1024..2047]

    const int c = blockIdx.x, b = blockIdx.y, t = threadIdx.x;
    const int w = t >> 6, lane = t & 63;
    const int kk = (lane >> 3) * 8;   // 8 k-groups of 8
    const int vv = (lane & 7) * 8;    // 8 v-groups of 8
    float* Ksw = &sm[w][0];
    float* Vsw = &sm[w][1024];

    const size_t row0 = (size_t)b * N_ + (size_t)c * 128 + (size_t)w * 32;
    const float4* K4 = (const float4*)(K + row0 * DK_);   // 512 float4 (32 rows)
    const float4* V4 = (const float4*)(V + row0 * DV_);

    float acc[8][8] = {};

    #pragma unroll
    for (int r = 0; r < 2; ++r) {
        // batch 8 global loads (16 rows K + 16 rows V), then LDS-write
        float4 kb_[4], vb_[4];
        #pragma unroll
        for (int j = 0; j < 4; ++j) kb_[j] = K4[r * 256 + j * 64 + lane];
        #pragma unroll
        for (int j = 0; j < 4; ++j) vb_[j] = V4[r * 256 + j * 64 + lane];
        #pragma unroll
        for (int j = 0; j < 4; ++j) {
            ((float4*)Ksw)[j * 64 + lane] = kb_[j];
            ((float4*)Vsw)[j * 64 + lane] = vb_[j];
        }
        // wave-private: no barrier; compiler lgkmcnt covers ds_write->ds_read
        #pragma unroll 4
        for (int n = 0; n < 16; ++n) {
            alignas(16) float fk[8], fv[8];
            *(float4*)&fk[0] = *(const float4*)&Ksw[n * 64 + kk];
            *(float4*)&fk[4] = *(const float4*)&Ksw[n * 64 + kk + 4];
            *(float4*)&fv[0] = *(const float4*)&Vsw[n * 64 + vv];
            *(float4*)&fv[4] = *(const float4*)&Vsw[n * 64 + vv + 4];
            #pragma unroll
            for (int i = 0; i < 8; ++i)
                #pragma unroll
                for (int j = 0; j < 8; ++j)
                    acc[i][j] += fk[i] * fv[j];
        }
    }

    // epilogue: staged cross-wave reduce in red[4096] (= sm[0..1] reused).
    // Barrier FIRST: red aliases waves 0/1 tile regions still being read.
    __syncthreads();
    float* red = &sm[0][0];
    if (w == 0) {
        #pragma unroll
        for (int i = 0; i < 8; ++i) {
            *(float4*)&red[(kk + i) * 64 + vv]     = make_float4(acc[i][0], acc[i][1], acc[i][2], acc[i][3]);
            *(float4*)&red[(kk + i) * 64 + vv + 4] = make_float4(acc[i][4], acc[i][5], acc[i][6], acc[i][7]);
        }
    }
    __syncthreads();
    #pragma unroll
    for (int ww = 1; ww < 4; ++ww) {
        if (w == ww) {
            #pragma unroll
            for (int i = 0; i < 8; ++i) {
                float4 r0 = *(float4*)&red[(kk + i) * 64 + vv];
                float4 r1 = *(float4*)&red[(kk + i) * 64 + vv + 4];
                r0.x += acc[i][0]; r0.y += acc[i][1]; r0.z += acc[i][2]; r0.w += acc[i][3];
                r1.x += acc[i][4]; r1.y += acc[i][5]; r1.z += acc[i][6]; r1.w += acc[i][7];
                *(float4*)&red[(kk + i) * 64 + vv]     = r0;
                *(float4*)&red[(kk + i) * 64 + vv + 4] = r1;
            }
        }
        __syncthreads();
    }

    float4* P = (float4*)(part + ((size_t)c * B_ + b) * 4096);
    #pragma unroll
    for (int j = 0; j < 4; ++j)
        P[t + 256 * j] = ((const float4*)red)[t + 256 * j];
}

// ---------------- Phase 1b: reduce 64 partials -> ktv ----------------
// grid 256 x 256: one float per thread (65536 outputs), coalesced.
__global__ __launch_bounds__(256) void p1_reduce(
    const float* __restrict__ part, float* __restrict__ ktv)
{
    const int idx = blockIdx.x * 256 + threadIdx.x;   // [0, 65536)
    float s = 0.f;
    #pragma unroll 16
    for (int c = 0; c < CH_; ++c)
        s += part[(size_t)c * 65536 + idx];
    ktv[idx] = s;
}

// ---------------- Phase 2: out = q^T ktv ----------------
// grid (64, 16), 256 threads (4 waves). Wave w: 32 n at nb*128+w*32.
// ktv in LDS (reused 128x); q streamed direct in 16-deep float4 batches.
__global__ __launch_bounds__(256) void p2(
    const float* __restrict__ q, const float* __restrict__ ktv,
    float* __restrict__ out)
{
    __shared__ float ks[4096];       // 16 KB: ktv[b], [k][v]

    const int nb = blockIdx.x, b = blockIdx.y, t = threadIdx.x;
    const int w = t >> 6, lane = t & 63;
    const int nl = (lane >> 3) * 4;  // 8 n-groups of 4
    const int vl = (lane & 7) * 8;   // 8 v-groups of 8
    const int n0 = nb * 128 + w * 32;

    const float4* kt4 = (const float4*)(ktv + (size_t)b * 4096);
    #pragma unroll
    for (int j = 0; j < 4; ++j)
        ((float4*)ks)[t + 256 * j] = kt4[t + 256 * j];
    __syncthreads();

    const float* ql = q + (size_t)b * DK_ * N_ + n0 + nl;   // + k*N_

    float acc[4][8] = {};
    #pragma unroll
    for (int kb = 0; kb < 4; ++kb) {
        // one 16-deep vmcnt batch of q rows kb*16..kb*16+15
        alignas(16) float fq[16][4];
        #pragma unroll
        for (int u = 0; u < 16; ++u)
            *(float4*)&fq[u][0] = *(const float4*)(ql + (size_t)(kb * 16 + u) * N_);
        #pragma unroll
        for (int u = 0; u < 16; ++u) {
            const int k = kb * 16 + u;
            alignas(16) float fv[8];
            *(float4*)&fv[0] = *(const float4*)&ks[k * 64 + vl];
            *(float4*)&fv[4] = *(const float4*)&ks[k * 64 + vl + 4];
            #pragma unroll
            for (int i = 0; i < 4; ++i)
                #pragma unroll
                for (int j = 0; j < 8; ++j)
                    acc[i][j] += fq[u][i] * fv[j];
        }
    }

    float* ob = out + ((size_t)b * N_ + n0 + nl) * DV_ + vl;
    #pragma unroll
    for (int i = 0; i < 4; ++i) {
        *(float4*)&ob[(size_t)i * DV_]     = make_float4(acc[i][0], acc[i][1], acc[i][2], acc[i][3]);
        *(float4*)&ob[(size_t)i * DV_ + 4] = make_float4(acc[i][4], acc[i][5], acc[i][6], acc[i][7]);
    }
}

extern "C" void kernel_launch(void* const* d_in, const int* in_sizes, int n_in,
                              void* d_out, int out_size, void* d_ws, size_t ws_size,
                              hipStream_t stream)
{
    (void)in_sizes; (void)n_in; (void)out_size; (void)ws_size;
    const float* q = (const float*)d_in[0];   // [16, 64, 8192]
    const float* k = (const float*)d_in[1];   // [16, 8192, 64]
    const float* v = (const float*)d_in[2];   // [16, 8192, 64]
    float* out = (float*)d_out;               // [16, 8192, 64]

    // ws: [64][16][4096] partials (16 MB) + [16][4096] ktv (256 KB)
    float* part = (float*)d_ws;
    float* ktv  = part + (size_t)CH_ * B_ * 4096;

    p1_partial<<<dim3(CH_, B_), 256, 0, stream>>>(k, v, part);
    p1_reduce<<<dim3(256), 256, 0, stream>>>(part, ktv);
    p2<<<dim3(64, B_), 256, 0, stream>>>(q, ktv, out);
}